// Round 7
// baseline (179.691 us; speedup 1.0000x reference)
//
#include <hip/hip_runtime.h>
#include <math.h>

#define NHEAD 4
#define DHEAD 32
#define NPIX  4096
#define CIN   128

typedef __bf16 bf16_t;
typedef __bf16 bf16x8 __attribute__((ext_vector_type(8)));
typedef __bf16 bf16x4 __attribute__((ext_vector_type(4)));
typedef float  f32x4  __attribute__((ext_vector_type(4)));

// 1/sqrt(32) * log2(e): folded into q weights so softmax exp is bare exp2.
constexpr float QSCALE = 0.17677669529663687f * 1.4426950408889634f;

// ---------------------------------------------------------------------------
// QKV projection, bf16 MFMA (unchanged from round 6 — isolate flash change).
// ---------------------------------------------------------------------------
__global__ void __launch_bounds__(384) qkv_mfma(
    const float* __restrict__ x, const float* __restrict__ wqkv,
    ushort* __restrict__ qb, ushort* __restrict__ kb, ushort* __restrict__ vT) {
  __shared__ ushort Xls[32 * 136];
  const int tid = threadIdx.x, cg = tid >> 6, lane = tid & 63;
  const int n = lane & 15, quad = lane >> 4;
  const int b = blockIdx.y, p0 = blockIdx.x * 32;

  const float wsc = (cg < 2) ? QSCALE : 1.0f;
  bf16x8 wf[4][4];
#pragma unroll
  for (int t1 = 0; t1 < 4; ++t1)
#pragma unroll
    for (int k = 0; k < 4; ++k) {
      const float* wp = wqkv + (size_t)(cg * 64 + t1 * 16 + n) * CIN + k * 32 + quad * 8;
      float4 a = *(const float4*)wp;
      float4 c = *(const float4*)(wp + 4);
      wf[t1][k] = (bf16x8){(bf16_t)(a.x * wsc), (bf16_t)(a.y * wsc),
                           (bf16_t)(a.z * wsc), (bf16_t)(a.w * wsc),
                           (bf16_t)(c.x * wsc), (bf16_t)(c.y * wsc),
                           (bf16_t)(c.z * wsc), (bf16_t)(c.w * wsc)};
    }

  if (tid < 256) {
    const int pc = tid & 7;
    const int c  = (tid >> 3) * 4;
    const float* xp = x + ((size_t)b * CIN + c) * NPIX + p0 + pc * 4;
    float4 r0 = *(const float4*)xp;
    float4 r1 = *(const float4*)(xp + NPIX);
    float4 r2 = *(const float4*)(xp + 2 * NPIX);
    float4 r3 = *(const float4*)(xp + 3 * NPIX);
    bf16x4 w0 = {(bf16_t)r0.x, (bf16_t)r1.x, (bf16_t)r2.x, (bf16_t)r3.x};
    bf16x4 w1 = {(bf16_t)r0.y, (bf16_t)r1.y, (bf16_t)r2.y, (bf16_t)r3.y};
    bf16x4 w2 = {(bf16_t)r0.z, (bf16_t)r1.z, (bf16_t)r2.z, (bf16_t)r3.z};
    bf16x4 w3 = {(bf16_t)r0.w, (bf16_t)r1.w, (bf16_t)r2.w, (bf16_t)r3.w};
    *(bf16x4*)&Xls[(pc * 4 + 0) * 136 + c] = w0;
    *(bf16x4*)&Xls[(pc * 4 + 1) * 136 + c] = w1;
    *(bf16x4*)&Xls[(pc * 4 + 2) * 136 + c] = w2;
    *(bf16x4*)&Xls[(pc * 4 + 3) * 136 + c] = w3;
  }
  __syncthreads();

  f32x4 acc[4][2];
#pragma unroll
  for (int i = 0; i < 4; ++i)
#pragma unroll
    for (int j = 0; j < 2; ++j) acc[i][j] = (f32x4){0.f, 0.f, 0.f, 0.f};

  const bool isv = (cg >= 4);
#pragma unroll
  for (int k = 0; k < 4; ++k) {
    bf16x8 xf[2];
#pragma unroll
    for (int pt = 0; pt < 2; ++pt)
      xf[pt] = *(const bf16x8*)&Xls[(pt * 16 + n) * 136 + k * 32 + quad * 8];
    if (!isv) {
#pragma unroll
      for (int wt = 0; wt < 4; ++wt)
#pragma unroll
        for (int pt = 0; pt < 2; ++pt)
          acc[wt][pt] = __builtin_amdgcn_mfma_f32_16x16x32_bf16(
              wf[wt][k], xf[pt], acc[wt][pt], 0, 0, 0);
    } else {
#pragma unroll
      for (int ct = 0; ct < 4; ++ct)
#pragma unroll
        for (int pt = 0; pt < 2; ++pt)
          acc[ct][pt] = __builtin_amdgcn_mfma_f32_16x16x32_bf16(
              xf[pt], wf[ct][k], acc[ct][pt], 0, 0, 0);
    }
  }

  if (!isv) {
    ushort* dst0 = (cg < 2) ? qb : kb;
#pragma unroll
    for (int wt = 0; wt < 4; ++wt) {
      const int ch = (cg & 1) * 64 + wt * 16 + quad * 4;
      const int head = ch >> 5, d = ch & 31;
#pragma unroll
      for (int pt = 0; pt < 2; ++pt) {
        const int p = p0 + pt * 16 + n;
        f32x4 a = acc[wt][pt];
        bf16x4 o = {(bf16_t)a[0], (bf16_t)a[1], (bf16_t)a[2], (bf16_t)a[3]};
        *(bf16x4*)(dst0 + ((size_t)(b * NHEAD + head) * NPIX + p) * DHEAD + d) = o;
      }
    }
  } else {
#pragma unroll
    for (int ct = 0; ct < 4; ++ct) {
      const int ch = (cg & 1) * 64 + ct * 16 + n;
      const int head = ch >> 5, d = ch & 31;
#pragma unroll
      for (int pt = 0; pt < 2; ++pt) {
        const int p = p0 + pt * 16 + quad * 4;
        f32x4 a = acc[ct][pt];
        bf16x4 o = {(bf16_t)a[0], (bf16_t)a[1], (bf16_t)a[2], (bf16_t)a[3]};
        *(bf16x4*)(vT + ((size_t)(b * NHEAD + head) * DHEAD + d) * NPIX + p) = o;
      }
    }
  }
}

// ---------------------------------------------------------------------------
// Flash attention v5: occupancy + ILP.
//  - wave = 32 queries (rp=2) x 1024 keys -> 8192 waves, 2048 blocks
//    (8/CU oversubscribed; LDS 17.4 KB; __launch_bounds__(256,5) -> ~20
//    resident waves/CU vs 10.6 in v4).
//  - batched step: all 4 QK MFMAs, then all 16 exp2+packs, then all 6
//    PV/l MFMAs -> no rp-serial dependency chain.
//  - XCD decode kept (FETCH stays ~6 MB): xcd=id&7, bh=xcd*2+((id>>3)&1),
//    qtile = id>>4 (128 per bh).
//  - permuted-key S^T trick: exp2 C-layout == PV A-layout, LDS-free loop;
//    l via ones-MFMA; one-barrier LDS combine; bf16 aoT out.
// ---------------------------------------------------------------------------
__device__ __forceinline__ void fl_load(const ushort* kb0, const ushort* vb0,
                                        int st, bf16x8* f) {
  f[0] = *(const bf16x8*)(kb0 + (size_t)(st * 32) * DHEAD);
  f[1] = *(const bf16x8*)(kb0 + (size_t)(st * 32 + 4) * DHEAD);
  f[2] = *(const bf16x8*)(vb0 + st * 32);
  f[3] = *(const bf16x8*)(vb0 + (size_t)16 * NPIX + st * 32);
}

__device__ __forceinline__ void fl_compute(const bf16x8* qf, const bf16x8* f,
                                           const bf16x8 ones,
                                           f32x4 O[2][2], f32x4* Ol) {
  const f32x4 zero = {0.f, 0.f, 0.f, 0.f};
  f32x4 s[2][2];
#pragma unroll
  for (int rp = 0; rp < 2; ++rp) {          // batch 1: all QK MFMAs
    s[rp][0] = __builtin_amdgcn_mfma_f32_16x16x32_bf16(f[0], qf[rp], zero, 0, 0, 0);
    s[rp][1] = __builtin_amdgcn_mfma_f32_16x16x32_bf16(f[1], qf[rp], zero, 0, 0, 0);
  }
  bf16x8 pf[2];
#pragma unroll
  for (int rp = 0; rp < 2; ++rp) {          // batch 2: all exp2 + packs
#pragma unroll
    for (int r = 0; r < 4; ++r) {
      pf[rp][r]     = (bf16_t)__builtin_amdgcn_exp2f(s[rp][0][r]);
      pf[rp][r + 4] = (bf16_t)__builtin_amdgcn_exp2f(s[rp][1][r]);
    }
  }
#pragma unroll
  for (int rp = 0; rp < 2; ++rp) {          // batch 3: all PV + l MFMAs
    O[rp][0] = __builtin_amdgcn_mfma_f32_16x16x32_bf16(pf[rp], f[2], O[rp][0], 0, 0, 0);
    O[rp][1] = __builtin_amdgcn_mfma_f32_16x16x32_bf16(pf[rp], f[3], O[rp][1], 0, 0, 0);
    Ol[rp]   = __builtin_amdgcn_mfma_f32_16x16x32_bf16(pf[rp], ones, Ol[rp], 0, 0, 0);
  }
}

__global__ void __launch_bounds__(256, 5) flash_mfma(
    const ushort* __restrict__ qb, const ushort* __restrict__ kbuf,
    const ushort* __restrict__ vTb, ushort* __restrict__ aoT) {
  __shared__ float Ols[4][32][34];   // [wave][q][d 0..31, l at 32]
  const int tid = threadIdx.x, wave = tid >> 6, lane = tid & 63;
  const int n = lane & 15, quad = lane >> 4;
  const int id = blockIdx.x;
  const int bh = (id & 7) * 2 + ((id >> 3) & 1);   // XCD-locality decode
  const int q0 = (id >> 4) * 32;

  const ushort* kg = kbuf + (size_t)bh * NPIX * DHEAD;
  const ushort* vg = vTb + (size_t)bh * DHEAD * NPIX;

  bf16x8 qf[2];
#pragma unroll
  for (int rp = 0; rp < 2; ++rp)
    qf[rp] = *(const bf16x8*)(qb +
        ((size_t)bh * NPIX + q0 + rp * 16 + n) * DHEAD + quad * 8);

  f32x4 O[2][2], Ol[2];
#pragma unroll
  for (int rp = 0; rp < 2; ++rp) {
    O[rp][0] = (f32x4){0.f, 0.f, 0.f, 0.f};
    O[rp][1] = (f32x4){0.f, 0.f, 0.f, 0.f};
    Ol[rp]   = (f32x4){0.f, 0.f, 0.f, 0.f};
  }
  const bf16_t one = (bf16_t)1.0f;
  const bf16x8 ones = {one, one, one, one, one, one, one, one};

  // permuted K row pi(n) = (n>>2)*8 + (n&3): exp2 C-layout == PV A-layout
  const int pk = ((n >> 2) << 3) | (n & 3);
  const ushort* kb0 = kg + (size_t)(wave * 1024 + pk) * DHEAD + quad * 8;
  const ushort* vb0 = vg + (size_t)n * NPIX + wave * 1024 + quad * 8;

  bf16x8 fA[4], fB[4];
  fl_load(kb0, vb0, 0, fA);
#pragma unroll 1
  for (int st = 0; st < 32; st += 2) {
    fl_load(kb0, vb0, st + 1, fB);
    fl_compute(qf, fA, ones, O, Ol);
    if (st + 2 < 32) fl_load(kb0, vb0, st + 2, fA);
    fl_compute(qf, fB, ones, O, Ol);
  }

  // cross-wave combine in LDS (one barrier), write normalized bf16 aoT
  float* W = &Ols[wave][0][0];
#pragma unroll
  for (int rp = 0; rp < 2; ++rp)
#pragma unroll
    for (int r = 0; r < 4; ++r) {
      const int q = rp * 16 + quad * 4 + r;
      W[q * 34 + n]      = O[rp][0][r];
      W[q * 34 + 16 + n] = O[rp][1][r];
      if (n == 0) W[q * 34 + 32] = Ol[rp][r];
    }
  __syncthreads();

  const int q = tid >> 3, dg = tid & 7;   // 32 q x 8 threads, 4 d each
  const float l = Ols[0][q][32] + Ols[1][q][32] + Ols[2][q][32] + Ols[3][q][32];
  const float inv = 1.f / l;
  f32x4 s0 = *(f32x4*)&Ols[0][q][dg * 4];
  f32x4 s1 = *(f32x4*)&Ols[1][q][dg * 4];
  f32x4 s2 = *(f32x4*)&Ols[2][q][dg * 4];
  f32x4 s3 = *(f32x4*)&Ols[3][q][dg * 4];
  bf16x4 o4 = {(bf16_t)((s0[0] + s1[0] + s2[0] + s3[0]) * inv),
               (bf16_t)((s0[1] + s1[1] + s2[1] + s3[1]) * inv),
               (bf16_t)((s0[2] + s1[2] + s2[2] + s3[2]) * inv),
               (bf16_t)((s0[3] + s1[3] + s2[3] + s3[3]) * inv)};
  *(bf16x4*)(aoT + ((size_t)bh * NPIX + q0 + q) * DHEAD + dg * 4) = o4;
}

// ---------------------------------------------------------------------------
// Output projection, bf16 MFMA (unchanged from round 6).
// ---------------------------------------------------------------------------
__global__ void __launch_bounds__(256) out_mfma(
    const ushort* __restrict__ aoT, const float* __restrict__ wout,
    const float* __restrict__ bias, float* __restrict__ out) {
  const int tid = threadIdx.x, wv = tid >> 6, lane = tid & 63;
  const int n = lane & 15, quad = lane >> 4;
  const int b = blockIdx.y;
  const int oc0 = (wv & 1) * 64;
  const int p = blockIdx.x * 32 + (wv >> 1) * 16 + n;

  bf16x8 wf[4][4];
#pragma unroll
  for (int mt = 0; mt < 4; ++mt)
#pragma unroll
    for (int k = 0; k < 4; ++k) {
      const float* wp = wout + (size_t)(oc0 + mt * 16 + n) * CIN + k * 32 + quad * 8;
      float4 a = *(const float4*)wp;
      float4 c = *(const float4*)(wp + 4);
      wf[mt][k] = (bf16x8){(bf16_t)a.x, (bf16_t)a.y, (bf16_t)a.z, (bf16_t)a.w,
                           (bf16_t)c.x, (bf16_t)c.y, (bf16_t)c.z, (bf16_t)c.w};
    }

  bf16x8 bfr[4];
#pragma unroll
  for (int k = 0; k < 4; ++k)
    bfr[k] = *(const bf16x8*)(aoT + ((size_t)(b * NHEAD + k) * NPIX + p) * DHEAD + quad * 8);

  f32x4 acc[4];
#pragma unroll
  for (int mt = 0; mt < 4; ++mt) acc[mt] = (f32x4){0.f, 0.f, 0.f, 0.f};
#pragma unroll
  for (int k = 0; k < 4; ++k)
#pragma unroll
    for (int mt = 0; mt < 4; ++mt)
      acc[mt] = __builtin_amdgcn_mfma_f32_16x16x32_bf16(wf[mt][k], bfr[k], acc[mt], 0, 0, 0);

#pragma unroll
  for (int mt = 0; mt < 4; ++mt) {
    const int oc = oc0 + mt * 16 + quad * 4;
#pragma unroll
    for (int r = 0; r < 4; ++r)
      out[((size_t)b * CIN + oc + r) * NPIX + p] = acc[mt][r] + bias[oc + r];
  }
}

// ---------------------------------------------------------------------------
extern "C" void kernel_launch(void* const* d_in, const int* in_sizes, int n_in,
                              void* d_out, int out_size, void* d_ws, size_t ws_size,
                              hipStream_t stream) {
  const float* x     = (const float*)d_in[0];   // [4,128,64,64]
  const float* w_qkv = (const float*)d_in[1];   // [384,128]
  const float* w_out = (const float*)d_in[2];   // [128,128]
  const float* b_out = (const float*)d_in[3];   // [128]
  float* out = (float*)d_out;                   // [4,128,64,64]

  // ws (bytes): qb 0 | kb 4M | vT 8M | aoT 12M..16M  (16 MB total)
  char* base = (char*)d_ws;
  ushort* qb  = (ushort*)base;
  ushort* kb  = (ushort*)(base + (size_t)4 * 1024 * 1024);
  ushort* vT  = (ushort*)(base + (size_t)8 * 1024 * 1024);
  ushort* aoT = (ushort*)(base + (size_t)12 * 1024 * 1024);

  qkv_mfma<<<dim3(128, 4), 384, 0, stream>>>(x, w_qkv, qb, kb, vT);
  flash_mfma<<<dim3(2048), 256, 0, stream>>>(qb, kb, vT, aoT);
  out_mfma<<<dim3(128, 4), 256, 0, stream>>>(aoT, w_out, b_out, out);
}

// Round 8
// 144.955 us; speedup vs baseline: 1.2396x; 1.2396x over previous
//
#include <hip/hip_runtime.h>
#include <math.h>

#define NHEAD 4
#define DHEAD 32
#define NPIX  4096
#define CIN   128
#define KTILE 128

typedef __bf16 bf16_t;
typedef __bf16 bf16x8 __attribute__((ext_vector_type(8)));
typedef __bf16 bf16x4 __attribute__((ext_vector_type(4)));
typedef float  f32x4  __attribute__((ext_vector_type(4)));

// 1/sqrt(32) * log2(e): folded into q weights so softmax exp is bare exp2.
constexpr float QSCALE = 0.17677669529663687f * 1.4426950408889634f;

// ---------------------------------------------------------------------------
// prep_swz: cast weights to bf16 AND pre-swizzle into MFMA fragment order so
// qkv/out weight loads are wave-contiguous 1KB blocks (fixes the 16-line
// lane-scatter that dominated qkv/out: lane n strided 512B in row-major w).
// wq_s[((cg*16 + t1*4 + k)*64 + lane)*8 + e], q rows pre-scaled by QSCALE.
// wo_s[((h*16 + mt*4 + k)*64 + lane)*8 + e].
// ---------------------------------------------------------------------------
__global__ void __launch_bounds__(256) prep_swz(
    const float* __restrict__ wqkv, const float* __restrict__ wout,
    ushort* __restrict__ wq_s, ushort* __restrict__ wo_s) {
  const int gid = blockIdx.x * 256 + threadIdx.x;   // 0..8191
  if (gid < 6144) {
    const int lane = gid & 63, n = lane & 15, quad = lane >> 4;
    const int fragid = gid >> 6;                    // 0..95
    const int cg = fragid >> 4, t1 = (fragid >> 2) & 3, k = fragid & 3;
    const float sc = (cg < 2) ? QSCALE : 1.f;
    const float* src = wqkv + (size_t)(cg * 64 + t1 * 16 + n) * CIN + k * 32 + quad * 8;
    bf16x8 o;
#pragma unroll
    for (int e = 0; e < 8; ++e) o[e] = (bf16_t)(src[e] * sc);
    *(bf16x8*)(wq_s + (size_t)gid * 8) = o;
  } else {
    const int oid = gid - 6144;                     // 0..2047
    const int lane = oid & 63, n = lane & 15, quad = lane >> 4;
    const int fragid = oid >> 6;                    // 0..31
    const int h = fragid >> 4, mt = (fragid >> 2) & 3, k = fragid & 3;
    const float* src = wout + (size_t)(h * 64 + mt * 16 + n) * CIN + k * 32 + quad * 8;
    bf16x8 o;
#pragma unroll
    for (int e = 0; e < 8; ++e) o[e] = (bf16_t)src[e];
    *(bf16x8*)(wo_s + (size_t)oid * 8) = o;
  }
}

// ---------------------------------------------------------------------------
// QKV projection, bf16 MFMA, swizzled-weight loads (wave-contiguous).
// Wave cg owns 64 out-channels (0,1=q 2,3=k 4,5=v). x tile staged transposed
// to LDS [p][c] (stride 136). v waves swap mfma operand order -> pixel-major
// C -> packed b64 stores into vT[d][p]. grid (128 ptiles, 4 batch), block 384.
// ---------------------------------------------------------------------------
__global__ void __launch_bounds__(384) qkv_mfma(
    const float* __restrict__ x, const ushort* __restrict__ wswz,
    ushort* __restrict__ qb, ushort* __restrict__ kb, ushort* __restrict__ vT) {
  __shared__ ushort Xls[32 * 136];
  const int tid = threadIdx.x, cg = tid >> 6, lane = tid & 63;
  const int n = lane & 15, quad = lane >> 4;
  const int b = blockIdx.y, p0 = blockIdx.x * 32;

  bf16x8 wf[4][4];
  {
    const ushort* wbase = wswz + (size_t)cg * 8192;
#pragma unroll
    for (int t1 = 0; t1 < 4; ++t1)
#pragma unroll
      for (int k = 0; k < 4; ++k)
        wf[t1][k] = *(const bf16x8*)(wbase + ((t1 * 4 + k) * 64 + lane) * 8);
  }

  if (tid < 256) {
    const int pc = tid & 7;
    const int c  = (tid >> 3) * 4;
    const float* xp = x + ((size_t)b * CIN + c) * NPIX + p0 + pc * 4;
    float4 r0 = *(const float4*)xp;
    float4 r1 = *(const float4*)(xp + NPIX);
    float4 r2 = *(const float4*)(xp + 2 * NPIX);
    float4 r3 = *(const float4*)(xp + 3 * NPIX);
    bf16x4 w0 = {(bf16_t)r0.x, (bf16_t)r1.x, (bf16_t)r2.x, (bf16_t)r3.x};
    bf16x4 w1 = {(bf16_t)r0.y, (bf16_t)r1.y, (bf16_t)r2.y, (bf16_t)r3.y};
    bf16x4 w2 = {(bf16_t)r0.z, (bf16_t)r1.z, (bf16_t)r2.z, (bf16_t)r3.z};
    bf16x4 w3 = {(bf16_t)r0.w, (bf16_t)r1.w, (bf16_t)r2.w, (bf16_t)r3.w};
    *(bf16x4*)&Xls[(pc * 4 + 0) * 136 + c] = w0;
    *(bf16x4*)&Xls[(pc * 4 + 1) * 136 + c] = w1;
    *(bf16x4*)&Xls[(pc * 4 + 2) * 136 + c] = w2;
    *(bf16x4*)&Xls[(pc * 4 + 3) * 136 + c] = w3;
  }
  __syncthreads();

  f32x4 acc[4][2];
#pragma unroll
  for (int i = 0; i < 4; ++i)
#pragma unroll
    for (int j = 0; j < 2; ++j) acc[i][j] = (f32x4){0.f, 0.f, 0.f, 0.f};

  const bool isv = (cg >= 4);
#pragma unroll
  for (int k = 0; k < 4; ++k) {
    bf16x8 xf[2];
#pragma unroll
    for (int pt = 0; pt < 2; ++pt)
      xf[pt] = *(const bf16x8*)&Xls[(pt * 16 + n) * 136 + k * 32 + quad * 8];
    if (!isv) {
#pragma unroll
      for (int wt = 0; wt < 4; ++wt)
#pragma unroll
        for (int pt = 0; pt < 2; ++pt)
          acc[wt][pt] = __builtin_amdgcn_mfma_f32_16x16x32_bf16(
              wf[wt][k], xf[pt], acc[wt][pt], 0, 0, 0);
    } else {
#pragma unroll
      for (int ct = 0; ct < 4; ++ct)
#pragma unroll
        for (int pt = 0; pt < 2; ++pt)
          acc[ct][pt] = __builtin_amdgcn_mfma_f32_16x16x32_bf16(
              xf[pt], wf[ct][k], acc[ct][pt], 0, 0, 0);
    }
  }

  if (!isv) {
    ushort* dst0 = (cg < 2) ? qb : kb;
#pragma unroll
    for (int wt = 0; wt < 4; ++wt) {
      const int ch = (cg & 1) * 64 + wt * 16 + quad * 4;
      const int head = ch >> 5, d = ch & 31;
#pragma unroll
      for (int pt = 0; pt < 2; ++pt) {
        const int p = p0 + pt * 16 + n;
        f32x4 a = acc[wt][pt];
        bf16x4 o = {(bf16_t)a[0], (bf16_t)a[1], (bf16_t)a[2], (bf16_t)a[3]};
        *(bf16x4*)(dst0 + ((size_t)(b * NHEAD + head) * NPIX + p) * DHEAD + d) = o;
      }
    }
  } else {
#pragma unroll
    for (int ct = 0; ct < 4; ++ct) {
      const int ch = (cg & 1) * 64 + ct * 16 + n;
      const int head = ch >> 5, d = ch & 31;
#pragma unroll
      for (int pt = 0; pt < 2; ++pt) {
        const int p = p0 + pt * 16 + quad * 4;
        f32x4 a = acc[ct][pt];
        bf16x4 o = {(bf16_t)a[0], (bf16_t)a[1], (bf16_t)a[2], (bf16_t)a[3]};
        *(bf16x4*)(vT + ((size_t)(b * NHEAD + head) * DHEAD + d) * NPIX + p) = o;
      }
    }
  }
}

// ---------------------------------------------------------------------------
// Flash attention v6: LDS-staged shared K/V.
// Block = 4 waves x 64 queries = 256q tile; ALL waves traverse the SAME keys
// (key-split 4 across blocks -> part buffer + combine4). K/V staged into LDS
// in 128-key double-buffered tiles with fully COALESCED global loads (fixes
// the L1 line-scatter bottleneck: was 16 lines/frag-load, 1 GB of scattered
// traffic; now 134 MB coalesced, fetched once per block, shared by 4 waves).
// K LDS rows unpadded (reads conflict-free by bank math); V rows padded to
// 136 ushorts (stride 272B -> 8 accesses/bank = minimum).
// Permuted-key S^T trick unchanged: exp2 C-layout == PV A-layout; l via
// ones-MFMA. grid 1024 blocks (XCD decode: xcd=id&7, bh=xcd*2+((id>>3)&1),
// qt=(id>>4)&15, ks=id>>8), block 256, LDS 33.8 KB -> 4 blocks/CU.
// ---------------------------------------------------------------------------
__global__ void __launch_bounds__(256, 4) flash_mfma(
    const ushort* __restrict__ qb, const ushort* __restrict__ kbuf,
    const ushort* __restrict__ vTb, float* __restrict__ part) {
  __shared__ ushort Kls[2][KTILE * 32];   // [key][d]
  __shared__ ushort Vls[2][32 * 136];     // [d][key], padded rows

  const int tid = threadIdx.x, wave = tid >> 6, lane = tid & 63;
  const int n = lane & 15, quad = lane >> 4;
  const int id = blockIdx.x;
  const int bh = (id & 7) * 2 + ((id >> 3) & 1);
  const int r  = id >> 4;                 // 0..63
  const int qt = r & 15;                  // 256q tile
  const int ks = r >> 4;                  // key split 0..3
  const int q0 = qt * 256 + wave * 64;
  const int k0 = ks * 1024;

  const ushort* kg = kbuf + (size_t)bh * NPIX * DHEAD + (size_t)k0 * DHEAD;
  const ushort* vg = vTb + (size_t)bh * DHEAD * NPIX + k0;

  bf16x8 qf[4];
#pragma unroll
  for (int rp = 0; rp < 4; ++rp)
    qf[rp] = *(const bf16x8*)(qb +
        ((size_t)bh * NPIX + q0 + rp * 16 + n) * DHEAD + quad * 8);

  f32x4 O[4][2], Ol[4];
#pragma unroll
  for (int rp = 0; rp < 4; ++rp) {
    O[rp][0] = (f32x4){0.f, 0.f, 0.f, 0.f};
    O[rp][1] = (f32x4){0.f, 0.f, 0.f, 0.f};
    Ol[rp]   = (f32x4){0.f, 0.f, 0.f, 0.f};
  }
  const bf16_t one = (bf16_t)1.0f;
  const bf16x8 ones = {one, one, one, one, one, one, one, one};
  const f32x4 zero = {0.f, 0.f, 0.f, 0.f};

  // staging thread mapping (coalesced 16B/lane):
  const int skey = tid >> 2, sseg = tid & 3;    // K: 64 keys x 4 segs / round
  const int sd   = tid >> 4, svs  = tid & 15;   // V: 16 d-rows x 16 segs / round
  // permuted K row pi(n) = (n>>2)*8 + (n&3): exp2 C-layout == PV A-layout
  const int pk = ((n >> 2) << 3) | (n & 3);

  bf16x8 kv0, kv1, vv0, vv1;
  // prologue: stage tile 0
  kv0 = *(const bf16x8*)(kg + (size_t)skey * DHEAD + sseg * 8);
  kv1 = *(const bf16x8*)(kg + (size_t)(skey + 64) * DHEAD + sseg * 8);
  vv0 = *(const bf16x8*)(vg + (size_t)sd * NPIX + svs * 8);
  vv1 = *(const bf16x8*)(vg + (size_t)(sd + 16) * NPIX + svs * 8);
  *(bf16x8*)&Kls[0][skey * 32 + sseg * 8]       = kv0;
  *(bf16x8*)&Kls[0][(skey + 64) * 32 + sseg * 8] = kv1;
  *(bf16x8*)&Vls[0][sd * 136 + svs * 8]          = vv0;
  *(bf16x8*)&Vls[0][(sd + 16) * 136 + svs * 8]   = vv1;
  __syncthreads();

#pragma unroll 1
  for (int tile = 0; tile < 8; ++tile) {
    const int cur = tile & 1;
    if (tile < 7) {                       // issue next tile's global loads
      const ushort* kgt = kg + (size_t)(tile + 1) * KTILE * DHEAD;
      const ushort* vgt = vg + (tile + 1) * KTILE;
      kv0 = *(const bf16x8*)(kgt + (size_t)skey * DHEAD + sseg * 8);
      kv1 = *(const bf16x8*)(kgt + (size_t)(skey + 64) * DHEAD + sseg * 8);
      vv0 = *(const bf16x8*)(vgt + (size_t)sd * NPIX + svs * 8);
      vv1 = *(const bf16x8*)(vgt + (size_t)(sd + 16) * NPIX + svs * 8);
    }

#pragma unroll
    for (int sub = 0; sub < 4; ++sub) {   // 4 x 32-key substeps
      const ushort* Kb = &Kls[cur][sub * 32 * 32];
      const bf16x8 f0 = *(const bf16x8*)&Kb[pk * 32 + quad * 8];
      const bf16x8 f1 = *(const bf16x8*)&Kb[(pk + 4) * 32 + quad * 8];
      const bf16x8 f2 = *(const bf16x8*)&Vls[cur][n * 136 + sub * 32 + quad * 8];
      const bf16x8 f3 = *(const bf16x8*)&Vls[cur][(n + 16) * 136 + sub * 32 + quad * 8];
#pragma unroll
      for (int hp = 0; hp < 2; ++hp) {    // rp in pairs: batched QK/exp/PV
        f32x4 s[2][2];
#pragma unroll
        for (int j = 0; j < 2; ++j) {
          s[j][0] = __builtin_amdgcn_mfma_f32_16x16x32_bf16(f0, qf[hp * 2 + j], zero, 0, 0, 0);
          s[j][1] = __builtin_amdgcn_mfma_f32_16x16x32_bf16(f1, qf[hp * 2 + j], zero, 0, 0, 0);
        }
        bf16x8 pf[2];
#pragma unroll
        for (int j = 0; j < 2; ++j)
#pragma unroll
          for (int rr = 0; rr < 4; ++rr) {
            pf[j][rr]     = (bf16_t)__builtin_amdgcn_exp2f(s[j][0][rr]);
            pf[j][rr + 4] = (bf16_t)__builtin_amdgcn_exp2f(s[j][1][rr]);
          }
#pragma unroll
        for (int j = 0; j < 2; ++j) {
          const int rp = hp * 2 + j;
          O[rp][0] = __builtin_amdgcn_mfma_f32_16x16x32_bf16(pf[j], f2, O[rp][0], 0, 0, 0);
          O[rp][1] = __builtin_amdgcn_mfma_f32_16x16x32_bf16(pf[j], f3, O[rp][1], 0, 0, 0);
          Ol[rp]   = __builtin_amdgcn_mfma_f32_16x16x32_bf16(pf[j], ones, Ol[rp], 0, 0, 0);
        }
      }
    }

    if (tile < 7) {                       // write next tile into other buffer
      const int nb = cur ^ 1;
      *(bf16x8*)&Kls[nb][skey * 32 + sseg * 8]        = kv0;
      *(bf16x8*)&Kls[nb][(skey + 64) * 32 + sseg * 8] = kv1;
      *(bf16x8*)&Vls[nb][sd * 136 + svs * 8]          = vv0;
      *(bf16x8*)&Vls[nb][(sd + 16) * 136 + svs * 8]   = vv1;
    }
    __syncthreads();
  }

  // epilogue: unnormalized partials (O, l) per (query, split)
  float* pb = part + ((size_t)ks * 65536 + (size_t)bh * NPIX + q0) * 36;
#pragma unroll
  for (int rp = 0; rp < 4; ++rp)
#pragma unroll
    for (int rr = 0; rr < 4; ++rr) {
      const int q = rp * 16 + quad * 4 + rr;
      pb[(size_t)q * 36 + n]      = O[rp][0][rr];
      pb[(size_t)q * 36 + 16 + n] = O[rp][1][rr];
      if (n == 0) pb[(size_t)q * 36 + 32] = Ol[rp][rr];
    }
}

// ---------------------------------------------------------------------------
// Combine the 4 key-split partials -> aoT[bh][pix][32] bf16.
// ---------------------------------------------------------------------------
__global__ void __launch_bounds__(256) combine4(
    const float* __restrict__ part, ushort* __restrict__ aoT) {
  const int idx = blockIdx.x * 256 + threadIdx.x;   // bh*4096 + q
  const float* p0 = part + (size_t)idx * 36;
  const float* p1 = p0 + (size_t)65536 * 36;
  const float* p2 = p1 + (size_t)65536 * 36;
  const float* p3 = p2 + (size_t)65536 * 36;
  const float inv = 1.f / (p0[32] + p1[32] + p2[32] + p3[32]);
#pragma unroll
  for (int t = 0; t < 4; ++t) {
    float4 a0 = ((const float4*)p0)[2 * t], a1 = ((const float4*)p0)[2 * t + 1];
    float4 b0 = ((const float4*)p1)[2 * t], b1 = ((const float4*)p1)[2 * t + 1];
    float4 c0 = ((const float4*)p2)[2 * t], c1 = ((const float4*)p2)[2 * t + 1];
    float4 d0 = ((const float4*)p3)[2 * t], d1 = ((const float4*)p3)[2 * t + 1];
    bf16x8 o = {(bf16_t)((a0.x + b0.x + c0.x + d0.x) * inv),
                (bf16_t)((a0.y + b0.y + c0.y + d0.y) * inv),
                (bf16_t)((a0.z + b0.z + c0.z + d0.z) * inv),
                (bf16_t)((a0.w + b0.w + c0.w + d0.w) * inv),
                (bf16_t)((a1.x + b1.x + c1.x + d1.x) * inv),
                (bf16_t)((a1.y + b1.y + c1.y + d1.y) * inv),
                (bf16_t)((a1.z + b1.z + c1.z + d1.z) * inv),
                (bf16_t)((a1.w + b1.w + c1.w + d1.w) * inv)};
    *(bf16x8*)(aoT + (size_t)idx * 32 + t * 8) = o;
  }
}

// ---------------------------------------------------------------------------
// Output projection, bf16 MFMA, swizzled-weight loads. Block 256 (4 waves):
// wave = 16 px x 64 oc. grid (128 ptiles of 32px, 4 batch) = 512 blocks.
// ---------------------------------------------------------------------------
__global__ void __launch_bounds__(256) out_mfma(
    const ushort* __restrict__ aoT, const ushort* __restrict__ wswz,
    const float* __restrict__ bias, float* __restrict__ out) {
  const int tid = threadIdx.x, wv = tid >> 6, lane = tid & 63;
  const int n = lane & 15, quad = lane >> 4;
  const int b = blockIdx.y;
  const int h = wv & 1;                  // oc half
  const int oc0 = h * 64;
  const int p = blockIdx.x * 32 + (wv >> 1) * 16 + n;

  bf16x8 wf[4][4];
  {
    const ushort* wbase = wswz + (size_t)h * 8192;
#pragma unroll
    for (int mt = 0; mt < 4; ++mt)
#pragma unroll
      for (int k = 0; k < 4; ++k)
        wf[mt][k] = *(const bf16x8*)(wbase + ((mt * 4 + k) * 64 + lane) * 8);
  }

  bf16x8 bfr[4];
#pragma unroll
  for (int k = 0; k < 4; ++k)
    bfr[k] = *(const bf16x8*)(aoT + ((size_t)(b * NHEAD + k) * NPIX + p) * DHEAD + quad * 8);

  f32x4 acc[4];
#pragma unroll
  for (int mt = 0; mt < 4; ++mt) acc[mt] = (f32x4){0.f, 0.f, 0.f, 0.f};
#pragma unroll
  for (int k = 0; k < 4; ++k)
#pragma unroll
    for (int mt = 0; mt < 4; ++mt)
      acc[mt] = __builtin_amdgcn_mfma_f32_16x16x32_bf16(wf[mt][k], bfr[k], acc[mt], 0, 0, 0);

#pragma unroll
  for (int mt = 0; mt < 4; ++mt) {
    const int oc = oc0 + mt * 16 + quad * 4;
#pragma unroll
    for (int rr = 0; rr < 4; ++rr)
      out[((size_t)b * CIN + oc + rr) * NPIX + p] = acc[mt][rr] + bias[oc + rr];
  }
}

// ---------------------------------------------------------------------------
extern "C" void kernel_launch(void* const* d_in, const int* in_sizes, int n_in,
                              void* d_out, int out_size, void* d_ws, size_t ws_size,
                              hipStream_t stream) {
  const float* x     = (const float*)d_in[0];   // [4,128,64,64]
  const float* w_qkv = (const float*)d_in[1];   // [384,128]
  const float* w_out = (const float*)d_in[2];   // [128,128]
  const float* b_out = (const float*)d_in[3];   // [128]
  float* out = (float*)d_out;                   // [4,128,64,64]

  // ws (bytes): qb 0 | kb 4M | vT 8M | aoT 12M | wq_s 16M | wo_s 16M+96K
  //             | part 17M .. 17M+37.75M  (~55 MB total)
  char* base = (char*)d_ws;
  ushort* qb   = (ushort*)base;
  ushort* kb   = (ushort*)(base + (size_t)4 * 1024 * 1024);
  ushort* vT   = (ushort*)(base + (size_t)8 * 1024 * 1024);
  ushort* aoT  = (ushort*)(base + (size_t)12 * 1024 * 1024);
  ushort* wq_s = (ushort*)(base + (size_t)16 * 1024 * 1024);
  ushort* wo_s = (ushort*)(base + (size_t)16 * 1024 * 1024 + 96 * 1024);
  float*  part = (float*)(base + (size_t)17 * 1024 * 1024);

  prep_swz<<<dim3(32), 256, 0, stream>>>(w_qkv, w_out, wq_s, wo_s);
  qkv_mfma<<<dim3(128, 4), 384, 0, stream>>>(x, wq_s, qb, kb, vT);
  flash_mfma<<<dim3(1024), 256, 0, stream>>>(qb, kb, vT, part);
  combine4<<<dim3(256), 256, 0, stream>>>(part, aoT);
  out_mfma<<<dim3(128, 4), 256, 0, stream>>>(aoT, wo_s, b_out, out);
}